// Round 2
// baseline (9.871 us; speedup 1.0000x reference)
//
#include <hip/hip_runtime.h>

typedef unsigned int uint32x4 __attribute__((ext_vector_type(4)));

__device__ __forceinline__ void full_add(uint32x4 a, uint32x4 b, uint32x4 c,
                                         uint32x4& s, uint32x4& co) {
    uint32x4 t = a ^ b;
    s  = t ^ c;
    co = (a & b) | (c & t);
}

// Majority vote over V=8 voters, bit-sliced on 32-bit packed words.
// out[m] bit b = 1 iff popcount_v(bit b of src[v][m]) >= 5.
__global__ __launch_bounds__(256) void majority8_kernel(
        const uint32x4* __restrict__ src,   // V * M4 vectors (voter-major)
        uint32x4* __restrict__ out,         // M4 vectors
        int M4) {
    int idx = blockIdx.x * blockDim.x + threadIdx.x;
    if (idx >= M4) return;

    uint32x4 x0 = src[0 * M4 + idx];
    uint32x4 x1 = src[1 * M4 + idx];
    uint32x4 x2 = src[2 * M4 + idx];
    uint32x4 x3 = src[3 * M4 + idx];
    uint32x4 x4 = src[4 * M4 + idx];
    uint32x4 x5 = src[5 * M4 + idx];
    uint32x4 x6 = src[6 * M4 + idx];
    uint32x4 x7 = src[7 * M4 + idx];

    // carry-save adder tree: per-bit count of 8 one-bit inputs
    uint32x4 s0, c0, s1, c1;
    full_add(x0, x1, x2, s0, c0);
    full_add(x3, x4, x5, s1, c1);
    uint32x4 s2 = x6 ^ x7;          // half adder
    uint32x4 c2 = x6 & x7;

    uint32x4 S, C, S2, C2;
    full_add(s0, s1, s2, S, C);     // S = ones bit, C = twos
    full_add(c0, c1, c2, S2, C2);   // S2 = twos, C2 = fours

    uint32x4 t = C ^ S2;            // twos bit of count
    uint32x4 u = C & S2;            // carries into fours
    uint32x4 f = C2 ^ u;            // fours bit of count
    uint32x4 e = C2 & u;            // eights bit of count

    // count >= 5  <=>  8 | (4 & (2|1))
    out[idx] = e | (f & (t | S));
}

extern "C" void kernel_launch(void* const* d_in, const int* in_sizes, int n_in,
                              void* d_out, int out_size, void* d_ws, size_t ws_size,
                              hipStream_t stream) {
    // d_in[0] = para_temp (float32, unused); d_in[1] = src (int32, V*M)
    const uint32x4* src = (const uint32x4*)d_in[1];
    uint32x4* out = (uint32x4*)d_out;

    int M  = out_size;        // 1048576 packed words
    int M4 = M / 4;           // vectors of 4 words (M is a multiple of 4)

    int block = 256;
    int grid  = (M4 + block - 1) / block;   // 1024 blocks
    majority8_kernel<<<grid, block, 0, stream>>>(src, out, M4);
}